// Round 1
// baseline (30281.570 us; speedup 1.0000x reference)
//
#include <hip/hip_runtime.h>
#include <hip/hip_bf16.h>

#define TT 1024
#define NBLK 256

typedef __attribute__((ext_vector_type(8))) short v8s;
typedef __attribute__((ext_vector_type(4))) float v4f;

__device__ __forceinline__ unsigned short f2b(float f){
  union { float f; unsigned u; } v; v.f = f;
  unsigned r = v.u + 0x7FFFu + ((v.u >> 16) & 1u);
  return (unsigned short)(r >> 16);
}
__device__ __forceinline__ float sigm(float x){ return 1.f/(1.f+__expf(-x)); }
__device__ __forceinline__ float tanh_(float x){
  float xc = fminf(fmaxf(x, -15.f), 15.f);
  float e = __expf(2.f*xc);
  return (e-1.f)/(e+1.f);
}

// monotone-counter grid barrier; cnt zeroed by hipMemsetAsync each launch
__device__ __forceinline__ void gbar(unsigned* cnt, unsigned target){
  __syncthreads();
  if (threadIdx.x == 0){
    __threadfence();                       // release: drain h stores to device scope
    atomicAdd(cnt, 1u);
    while (__hip_atomic_load(cnt, __ATOMIC_RELAXED, __HIP_MEMORY_SCOPE_AGENT) < target)
      __builtin_amdgcn_s_sleep(8);
    __threadfence();                       // acquire: invalidate stale L1/L2
  }
  __syncthreads();
}

// One LSTM layer, persistent. Each block owns 8 hidden units (32 z-cols: 4 gates x 8).
// K (= KX input dims + 1024 recurrent dims) split across 8 waves, NK k-steps of 32 each.
// Weights resident in VGPRs as MFMA B-fragments for the whole sequence.
template<int NK, int KX, int XS, bool L2L>
__device__ void run_layer(const unsigned short* __restrict__ xseq,
                          unsigned short* __restrict__ hseq,
                          const float* __restrict__ Wx,
                          const float* __restrict__ Wh,
                          const float* __restrict__ bias,
                          unsigned* __restrict__ bar,
                          int ub,
                          float (*red)[32][33])
{
  const int tid  = threadIdx.x;
  const int lane = tid & 63;
  const int wave = tid >> 6;
  const int l15  = lane & 15;
  const int qd   = lane >> 4;
  const int q8   = qd * 8;

  // ---- one-time: load weight fragments (fp32 -> bf16) into registers ----
  v8s wf[NK][2];
  #pragma unroll
  for (int ks = 0; ks < NK; ++ks){
    #pragma unroll
    for (int nt = 0; nt < 2; ++nt){
      int c = nt*16 + l15;                       // local col 0..31
      int gcol = (c >> 3) * 1024 + ub + (c & 7); // gate*1024 + unit
      int kb = wave * (NK*32) + ks*32 + q8;
      #pragma unroll
      for (int j = 0; j < 8; ++j){
        int k = kb + j;
        float v = (k < KX) ? Wx[(size_t)k * 4096 + gcol]
                           : Wh[(size_t)(k - KX) * 4096 + gcol];
        wf[ks][nt][j] = (short)f2b(v);
      }
    }
  }

  // per-thread gate state: threads 0..255 handle (m = tid>>3, u = tid&7)
  float cst = 0.f;
  float bz[4] = {0.f,0.f,0.f,0.f};
  if (tid < 256){
    int u = tid & 7;
    #pragma unroll
    for (int g = 0; g < 4; ++g) bz[g] = bias[g*1024 + ub + u];
  }

  for (int w = 0; w <= TT; ++w){
    const bool active = L2L ? (w >= 1) : (w < TT);
    const int t = L2L ? (w - 1) : w;
    if (active){
      const unsigned short* xb = xseq + (size_t)(t + (L2L ? 1 : 0)) * (size_t)(XS * 32);
      const unsigned short* hb = hseq + (size_t)t * 32768;
      v4f acc[2][2];
      #pragma unroll
      for (int mt = 0; mt < 2; ++mt)
        #pragma unroll
        for (int nt = 0; nt < 2; ++nt)
          acc[mt][nt] = (v4f){0.f,0.f,0.f,0.f};

      #pragma unroll
      for (int ks = 0; ks < NK; ++ks){
        int k = wave*(NK*32) + ks*32;
        const unsigned short* src; int rs;
        if (k < KX){ src = xb + k;        rs = XS;   }
        else       { src = hb + (k - KX); rs = 1024; }
        const unsigned short* p = src + (size_t)l15 * rs + q8;
        v8s a0 = *(const v8s*)p;
        v8s a1 = *(const v8s*)(p + (size_t)16 * rs);
        acc[0][0] = __builtin_amdgcn_mfma_f32_16x16x32_bf16(a0, wf[ks][0], acc[0][0], 0,0,0);
        acc[0][1] = __builtin_amdgcn_mfma_f32_16x16x32_bf16(a0, wf[ks][1], acc[0][1], 0,0,0);
        acc[1][0] = __builtin_amdgcn_mfma_f32_16x16x32_bf16(a1, wf[ks][0], acc[1][0], 0,0,0);
        acc[1][1] = __builtin_amdgcn_mfma_f32_16x16x32_bf16(a1, wf[ks][1], acc[1][1], 0,0,0);
      }
      // C/D layout: col = lane&15, row = (lane>>4)*4 + r
      #pragma unroll
      for (int mt = 0; mt < 2; ++mt)
        #pragma unroll
        for (int nt = 0; nt < 2; ++nt)
          #pragma unroll
          for (int r = 0; r < 4; ++r)
            red[wave][mt*16 + qd*4 + r][nt*16 + l15] = acc[mt][nt][r];
    }
    __syncthreads();
    if (active && tid < 256){
      int m = tid >> 3, u = tid & 7;
      float z[4];
      #pragma unroll
      for (int g = 0; g < 4; ++g){
        float s = bz[g];
        #pragma unroll
        for (int w8 = 0; w8 < 8; ++w8) s += red[w8][m][g*8 + u];
        z[g] = s;
      }
      float i  = sigm(z[0]);
      float f  = sigm(z[1]);
      float gg = tanh_(z[2]);
      float o  = sigm(z[3]);
      cst = f*cst + i*gg;
      float hv = o * tanh_(cst);
      hseq[(size_t)(t+1) * 32768 + (size_t)m*1024 + ub + u] = f2b(hv);
    }
    gbar(bar, (unsigned)(w+1) * NBLK);
  }
}

__global__ __launch_bounds__(512, 2)
void lstm_persist(const unsigned short* __restrict__ obsb,
                  unsigned short* __restrict__ h1,
                  unsigned short* __restrict__ h2,
                  const float* __restrict__ W1x, const float* __restrict__ W1h,
                  const float* __restrict__ b1,
                  const float* __restrict__ W2x, const float* __restrict__ W2h,
                  const float* __restrict__ b2,
                  unsigned* __restrict__ bar)
{
  __shared__ float red[8][32][33];
  int blk = blockIdx.x;
  if (blk < 128){
    // layer 1: K = 256 (obs) + 1024 (h1), 8 waves x 5 ksteps x 32
    run_layer<5, 256, 256, false>(obsb, h1, W1x, W1h, b1, bar, blk*8, red);
  } else {
    // layer 2: K = 1024 (h1) + 1024 (h2), 8 waves x 8 ksteps x 32, 1-step skew
    run_layer<8, 1024, 1024, true>(h1, h2, W2x, W2h, b2, bar, (blk-128)*8, red);
  }
}

// obs [32,1024,256] fp32 -> obsb [t][m][k] bf16
__global__ void obs_conv(const float* __restrict__ obs, unsigned short* __restrict__ obsb){
  int idx = blockIdx.x * 256 + threadIdx.x;      // 2,097,152 total
  int k4 = idx & 63;
  int rest = idx >> 6;
  int m = rest & 31;
  int t = rest >> 5;
  const float4 v = *(const float4*)(obs + (size_t)m*262144 + (size_t)t*256 + k4*4);
  ushort4 o;
  o.x = f2b(v.x); o.y = f2b(v.y); o.z = f2b(v.z); o.w = f2b(v.w);
  *(ushort4*)(obsb + (size_t)t*8192 + m*256 + k4*4) = o;
}

// pack [Wm | Wc] -> BT[n][k] bf16 (transposed, n-major)
__global__ void head_pack(const float* __restrict__ Wm, const float* __restrict__ Wc,
                          unsigned short* __restrict__ wt){
  int idx = blockIdx.x * 256 + threadIdx.x;      // 1,048,576 total
  int k = idx & 1023;
  int n = idx >> 10;
  float v = (n < 512) ? Wm[(size_t)k*512 + n] : Wc[(size_t)k*512 + (n-512)];
  wt[(size_t)n*1024 + k] = f2b(v);
}

// heads: [32768,1024] x [1024,1024], epilogue adds bias, softplus on cov half
__global__ __launch_bounds__(256, 2)
void heads_gemm(const unsigned short* __restrict__ A,
                const unsigned short* __restrict__ BT,
                const float* __restrict__ bm, const float* __restrict__ bc,
                float* __restrict__ out)
{
  __shared__ short LA[128][40];
  __shared__ short LB[128][40];
  const int tid  = threadIdx.x;
  const int lane = tid & 63;
  const int wave = tid >> 6;
  const int wm = wave & 1, wn = wave >> 1;
  const int l15 = lane & 15, qd = lane >> 4;
  const int bm0 = blockIdx.x * 128;
  const int bn0 = blockIdx.y * 128;

  v4f acc[4][4];
  #pragma unroll
  for (int i = 0; i < 4; ++i)
    #pragma unroll
    for (int j = 0; j < 4; ++j)
      acc[i][j] = (v4f){0.f,0.f,0.f,0.f};

  for (int k0 = 0; k0 < 1024; k0 += 32){
    __syncthreads();
    #pragma unroll
    for (int i = 0; i < 2; ++i){
      int c = tid + i*256;                 // 512 16B chunks each for A and B
      int row = c >> 2, kc = (c & 3) * 8;
      *(v8s*)&LA[row][kc] = *(const v8s*)&A [(size_t)(bm0 + row)*1024 + k0 + kc];
      *(v8s*)&LB[row][kc] = *(const v8s*)&BT[(size_t)(bn0 + row)*1024 + k0 + kc];
    }
    __syncthreads();
    v8s a[4], b[4];
    #pragma unroll
    for (int mt = 0; mt < 4; ++mt) a[mt] = *(const v8s*)&LA[wm*64 + mt*16 + l15][qd*8];
    #pragma unroll
    for (int nt = 0; nt < 4; ++nt) b[nt] = *(const v8s*)&LB[wn*64 + nt*16 + l15][qd*8];
    #pragma unroll
    for (int mt = 0; mt < 4; ++mt)
      #pragma unroll
      for (int nt = 0; nt < 4; ++nt)
        acc[mt][nt] = __builtin_amdgcn_mfma_f32_16x16x32_bf16(a[mt], b[nt], acc[mt][nt], 0,0,0);
  }

  #pragma unroll
  for (int mt = 0; mt < 4; ++mt){
    #pragma unroll
    for (int nt = 0; nt < 4; ++nt){
      #pragma unroll
      for (int r = 0; r < 4; ++r){
        int rg = bm0 + wm*64 + mt*16 + qd*4 + r;
        int cg = bn0 + wn*64 + nt*16 + l15;
        int t = rg >> 5, b_ = rg & 31;
        float v = acc[mt][nt][r];
        if (cg < 512){
          out[((size_t)b_*1024 + t)*512 + cg] = v + bm[cg];
        } else {
          float x = v + bc[cg - 512];
          float sp = fmaxf(x, 0.f) + log1pf(__expf(-fabsf(x)));
          out[(size_t)16777216 + ((size_t)b_*1024 + t)*512 + (cg - 512)] = sp;
        }
      }
    }
  }
}

extern "C" void kernel_launch(void* const* d_in, const int* in_sizes, int n_in,
                              void* d_out, int out_size, void* d_ws, size_t ws_size,
                              hipStream_t stream)
{
  const float* obs = (const float*)d_in[0];
  const float* W1x = (const float*)d_in[1];
  const float* W1h = (const float*)d_in[2];
  const float* b1  = (const float*)d_in[3];
  const float* W2x = (const float*)d_in[4];
  const float* W2h = (const float*)d_in[5];
  const float* b2  = (const float*)d_in[6];
  const float* Wm  = (const float*)d_in[7];
  const float* bm  = (const float*)d_in[8];
  const float* Wc  = (const float*)d_in[9];
  const float* bc  = (const float*)d_in[10];
  float* out = (float*)d_out;

  char* wsb = (char*)d_ws;
  unsigned* bar        = (unsigned*)wsb;
  unsigned short* h1   = (unsigned short*)(wsb + 4096);       // [1025][32][1024] bf16
  unsigned short* h2   = h1 + (size_t)1025*32768;             // [1025][32][1024] bf16
  unsigned short* obsb = h2 + (size_t)1025*32768;             // [1024][32][256]  bf16
  unsigned short* wht  = obsb + (size_t)1024*8192;            // [1024][1024]     bf16
  // total ws use: 4096 + 2*134'348'800/2... = ~153.4 MB

  hipMemsetAsync(bar, 0, 256, stream);
  hipMemsetAsync(h1, 0, 65536, stream);   // h1 slot 0 = h_{-1} = 0
  hipMemsetAsync(h2, 0, 65536, stream);   // h2 slot 0 = 0

  obs_conv <<<8192, 256, 0, stream>>>(obs, obsb);
  head_pack<<<4096, 256, 0, stream>>>(Wm, Wc, wht);

  const unsigned short* obsb_c = obsb;
  void* kargs[] = { (void*)&obsb_c, (void*)&h1, (void*)&h2,
                    (void*)&W1x, (void*)&W1h, (void*)&b1,
                    (void*)&W2x, (void*)&W2h, (void*)&b2, (void*)&bar };
  hipLaunchCooperativeKernel((void*)lstm_persist, dim3(NBLK), dim3(512), kargs, 0, stream);

  const unsigned short* Ah = h2 + 32768;   // h2 slots 1..1024 -> [32768,1024]
  heads_gemm<<<dim3(256, 8), 256, 0, stream>>>(Ah, wht, bm, bc, out);
}

// Round 2
// 10885.790 us; speedup vs baseline: 2.7818x; 2.7818x over previous
//
#include <hip/hip_runtime.h>
#include <hip/hip_bf16.h>

#define TT 1024
#define NBLK 256

typedef __attribute__((ext_vector_type(8))) short v8s;
typedef __attribute__((ext_vector_type(4))) float v4f;

__device__ __forceinline__ unsigned short f2b(float f){
  union { float f; unsigned u; } v; v.f = f;
  unsigned r = v.u + 0x7FFFu + ((v.u >> 16) & 1u);
  return (unsigned short)(r >> 16);
}
__device__ __forceinline__ float sigm(float x){ return 1.f/(1.f+__expf(-x)); }
__device__ __forceinline__ float tanh_(float x){
  float xc = fminf(fmaxf(x, -15.f), 15.f);
  float e = __expf(2.f*xc);
  return (e-1.f)/(e+1.f);
}

// Coherent (agent-scope, cache-bypass) 16B load as two 8B relaxed atomics.
// No buffer_inv / buffer_wbl2 — reads go to the device coherence point.
template<bool COH>
__device__ __forceinline__ v8s ldA(const unsigned short* p){
  if (COH){
    const unsigned long long* q = (const unsigned long long*)p;
    unsigned long long lo = __hip_atomic_load(q,     __ATOMIC_RELAXED, __HIP_MEMORY_SCOPE_AGENT);
    unsigned long long hi = __hip_atomic_load(q + 1, __ATOMIC_RELAXED, __HIP_MEMORY_SCOPE_AGENT);
    union { unsigned long long q[2]; v8s v; } u; u.q[0] = lo; u.q[1] = hi;
    return u.v;
  } else {
    return *(const v8s*)p;
  }
}

// Each lane spins on 2 of 128 per-block monotone flags (64B apart).
__device__ __forceinline__ void poll128(const unsigned* flags, int base, unsigned tgt, int lane){
  const unsigned* f0 = flags + (size_t)(base + lane) * 16;
  const unsigned* f1 = flags + (size_t)(base + lane + 64) * 16;
  unsigned a, b;
  do {
    a = __hip_atomic_load(f0, __ATOMIC_RELAXED, __HIP_MEMORY_SCOPE_AGENT);
    b = __hip_atomic_load(f1, __ATOMIC_RELAXED, __HIP_MEMORY_SCOPE_AGENT);
  } while (a < tgt || b < tgt);
}

// One LSTM layer, persistent. Each block owns 8 hidden units (32 z-cols: 4 gates x 8).
// K (= KX input dims + 1024 recurrent dims) split across 8 waves, NK k-steps of 32 each.
// Weights resident in VGPRs as MFMA B-fragments for the whole sequence.
// Cross-block h exchange via relaxed agent atomics (cache-bypass) + per-block flags.
template<int NK, int KX, int XS, bool L2L, int XFLAG, int HFLAG>
__device__ void run_layer(const unsigned short* __restrict__ xseq,
                          unsigned short* __restrict__ hseq,
                          const float* __restrict__ Wx,
                          const float* __restrict__ Wh,
                          const float* __restrict__ bias,
                          unsigned* __restrict__ flags,
                          int myidx, int ub,
                          float (*red)[32][36],
                          unsigned short* hstage)
{
  const int tid  = threadIdx.x;
  const int lane = tid & 63;
  const int wave = tid >> 6;
  const int l15  = lane & 15;
  const int qd   = lane >> 4;
  const int q8   = qd * 8;
  constexpr bool XCOH = (XFLAG >= 0);

  const int ksk   = wave * (NK * 32);
  const bool needX = XCOH && (ksk < KX);
  const bool needH = (ksk + NK * 32) > KX;

  unsigned* myflag = flags + (size_t)((XCOH ? HFLAG : XFLAG < 0 ? 0 : 0) + 0); // placeholder, set below
  myflag = flags + (size_t)((L2L ? 128 : 0) + myidx) * 16;

  // ---- one-time: load weight fragments (fp32 -> bf16) into registers ----
  v8s wf[NK][2];
  #pragma unroll
  for (int ks = 0; ks < NK; ++ks){
    #pragma unroll
    for (int nt = 0; nt < 2; ++nt){
      int c = nt*16 + l15;                       // local col 0..31
      int gcol = (c >> 3) * 1024 + ub + (c & 7); // gate*1024 + unit
      int kb = ksk + ks*32 + q8;
      #pragma unroll
      for (int j = 0; j < 8; ++j){
        int k = kb + j;
        float v = (k < KX) ? Wx[(size_t)k * 4096 + gcol]
                           : Wh[(size_t)(k - KX) * 4096 + gcol];
        wf[ks][nt][j] = (short)f2b(v);
      }
    }
  }

  // per-thread gate state: threads 0..255 handle (m = tid>>3, u = tid&7)
  float cst = 0.f;
  float bz[4] = {0.f,0.f,0.f,0.f};
  if (tid < 256){
    int u = tid & 7;
    #pragma unroll
    for (int g = 0; g < 4; ++g) bz[g] = bias[g*1024 + ub + u];
  }

  for (int w = 0; w <= TT; ++w){
    const bool active = L2L ? (w >= 1) : (w < TT);
    const int t = L2L ? (w - 1) : w;
    if (active){
      const unsigned tgt = (unsigned)w;
      if (needX) poll128(flags, XFLAG, tgt, lane);
      if (needH) poll128(flags, HFLAG, tgt, lane);

      const unsigned short* xb = xseq + (size_t)(t + (L2L ? 1 : 0)) * (size_t)(XS * 32);
      const unsigned short* hb = hseq + (size_t)t * 32768;
      v4f acc[2][2];
      #pragma unroll
      for (int mt = 0; mt < 2; ++mt)
        #pragma unroll
        for (int nt = 0; nt < 2; ++nt)
          acc[mt][nt] = (v4f){0.f,0.f,0.f,0.f};

      #pragma unroll
      for (int ks = 0; ks < NK; ++ks){
        int k = ksk + ks*32;
        v8s a0, a1;
        if (k < KX){
          const unsigned short* p = xb + k + (size_t)l15 * XS + q8;
          a0 = ldA<XCOH>(p);
          a1 = ldA<XCOH>(p + (size_t)16 * XS);
        } else {
          const unsigned short* p = hb + (k - KX) + (size_t)l15 * 1024 + q8;
          a0 = ldA<true>(p);
          a1 = ldA<true>(p + (size_t)16 * 1024);
        }
        acc[0][0] = __builtin_amdgcn_mfma_f32_16x16x32_bf16(a0, wf[ks][0], acc[0][0], 0,0,0);
        acc[0][1] = __builtin_amdgcn_mfma_f32_16x16x32_bf16(a0, wf[ks][1], acc[0][1], 0,0,0);
        acc[1][0] = __builtin_amdgcn_mfma_f32_16x16x32_bf16(a1, wf[ks][0], acc[1][0], 0,0,0);
        acc[1][1] = __builtin_amdgcn_mfma_f32_16x16x32_bf16(a1, wf[ks][1], acc[1][1], 0,0,0);
      }
      // C/D layout: col = lane&15, row = (lane>>4)*4 + r
      #pragma unroll
      for (int mt = 0; mt < 2; ++mt)
        #pragma unroll
        for (int nt = 0; nt < 2; ++nt)
          #pragma unroll
          for (int r = 0; r < 4; ++r)
            red[wave][mt*16 + qd*4 + r][nt*16 + l15] = acc[mt][nt][r];
    }
    __syncthreads();
    if (active && tid < 256){
      int m = tid >> 3, u = tid & 7;
      float z[4];
      #pragma unroll
      for (int g = 0; g < 4; ++g){
        float s = bz[g];
        #pragma unroll
        for (int w8 = 0; w8 < 8; ++w8) s += red[w8][m][g*8 + u];
        z[g] = s;
      }
      float i  = sigm(z[0]);
      float f  = sigm(z[1]);
      float gg = tanh_(z[2]);
      float o  = sigm(z[3]);
      cst = f*cst + i*gg;
      float hv = o * tanh_(cst);
      hstage[m*8 + u] = f2b(hv);
    }
    __syncthreads();
    if (tid < 64){
      if (active){
        unsigned long long v = ((const unsigned long long*)hstage)[tid];
        int row = tid >> 1, half = tid & 1;
        unsigned long long* dst = (unsigned long long*)
            (hseq + (size_t)(t+1)*32768 + (size_t)row*1024 + ub + half*4);
        __hip_atomic_store(dst, v, __ATOMIC_RELAXED, __HIP_MEMORY_SCOPE_AGENT);
      }
      __builtin_amdgcn_s_waitcnt(0);   // h stores globally visible before flag
      if (tid == 0)
        __hip_atomic_store(myflag, (unsigned)(w+1), __ATOMIC_RELAXED, __HIP_MEMORY_SCOPE_AGENT);
    }
  }
}

__global__ __launch_bounds__(512, 2)
void lstm_persist(const unsigned short* __restrict__ obsb,
                  unsigned short* __restrict__ h1,
                  unsigned short* __restrict__ h2,
                  const float* __restrict__ W1x, const float* __restrict__ W1h,
                  const float* __restrict__ b1,
                  const float* __restrict__ W2x, const float* __restrict__ W2h,
                  const float* __restrict__ b2,
                  unsigned* __restrict__ flags)
{
  __shared__ float red[8][32][36];
  __shared__ unsigned short hstage[256];
  int blk = blockIdx.x;
  if (blk < 128){
    // layer 1: K = 256 (obs, plain cached) + 1024 (h1, coherent), flags group 0
    run_layer<5, 256, 256, false, -1, 0>(obsb, h1, W1x, W1h, b1, flags, blk, blk*8, red, hstage);
  } else {
    // layer 2: K = 1024 (h1, coherent, flags group 0) + 1024 (h2, flags group 128)
    run_layer<8, 1024, 1024, true, 0, 128>(h1, h2, W2x, W2h, b2, flags, blk-128, (blk-128)*8, red, hstage);
  }
}

// obs [32,1024,256] fp32 -> obsb [t][m][k] bf16
__global__ void obs_conv(const float* __restrict__ obs, unsigned short* __restrict__ obsb){
  int idx = blockIdx.x * 256 + threadIdx.x;      // 2,097,152 total
  int k4 = idx & 63;
  int rest = idx >> 6;
  int m = rest & 31;
  int t = rest >> 5;
  const float4 v = *(const float4*)(obs + (size_t)m*262144 + (size_t)t*256 + k4*4);
  ushort4 o;
  o.x = f2b(v.x); o.y = f2b(v.y); o.z = f2b(v.z); o.w = f2b(v.w);
  *(ushort4*)(obsb + (size_t)t*8192 + m*256 + k4*4) = o;
}

// pack [Wm | Wc] -> BT[n][k] bf16 (transposed, n-major)
__global__ void head_pack(const float* __restrict__ Wm, const float* __restrict__ Wc,
                          unsigned short* __restrict__ wt){
  int idx = blockIdx.x * 256 + threadIdx.x;      // 1,048,576 total
  int k = idx & 1023;
  int n = idx >> 10;
  float v = (n < 512) ? Wm[(size_t)k*512 + n] : Wc[(size_t)k*512 + (n-512)];
  wt[(size_t)n*1024 + k] = f2b(v);
}

// heads: [32768,1024] x [1024,1024], epilogue adds bias, softplus on cov half
__global__ __launch_bounds__(256, 2)
void heads_gemm(const unsigned short* __restrict__ A,
                const unsigned short* __restrict__ BT,
                const float* __restrict__ bm, const float* __restrict__ bc,
                float* __restrict__ out)
{
  __shared__ short LA[128][40];
  __shared__ short LB[128][40];
  const int tid  = threadIdx.x;
  const int lane = tid & 63;
  const int wave = tid >> 6;
  const int wm = wave & 1, wn = wave >> 1;
  const int l15 = lane & 15, qd = lane >> 4;
  const int bm0 = blockIdx.x * 128;
  const int bn0 = blockIdx.y * 128;

  v4f acc[4][4];
  #pragma unroll
  for (int i = 0; i < 4; ++i)
    #pragma unroll
    for (int j = 0; j < 4; ++j)
      acc[i][j] = (v4f){0.f,0.f,0.f,0.f};

  for (int k0 = 0; k0 < 1024; k0 += 32){
    __syncthreads();
    #pragma unroll
    for (int i = 0; i < 2; ++i){
      int c = tid + i*256;                 // 512 16B chunks each for A and B
      int row = c >> 2, kc = (c & 3) * 8;
      *(v8s*)&LA[row][kc] = *(const v8s*)&A [(size_t)(bm0 + row)*1024 + k0 + kc];
      *(v8s*)&LB[row][kc] = *(const v8s*)&BT[(size_t)(bn0 + row)*1024 + k0 + kc];
    }
    __syncthreads();
    v8s a[4], b[4];
    #pragma unroll
    for (int mt = 0; mt < 4; ++mt) a[mt] = *(const v8s*)&LA[wm*64 + mt*16 + l15][qd*8];
    #pragma unroll
    for (int nt = 0; nt < 4; ++nt) b[nt] = *(const v8s*)&LB[wn*64 + nt*16 + l15][qd*8];
    #pragma unroll
    for (int mt = 0; mt < 4; ++mt)
      #pragma unroll
      for (int nt = 0; nt < 4; ++nt)
        acc[mt][nt] = __builtin_amdgcn_mfma_f32_16x16x32_bf16(a[mt], b[nt], acc[mt][nt], 0,0,0);
  }

  #pragma unroll
  for (int mt = 0; mt < 4; ++mt){
    #pragma unroll
    for (int nt = 0; nt < 4; ++nt){
      #pragma unroll
      for (int r = 0; r < 4; ++r){
        int rg = bm0 + wm*64 + mt*16 + qd*4 + r;
        int cg = bn0 + wn*64 + nt*16 + l15;
        int t = rg >> 5, b_ = rg & 31;
        float v = acc[mt][nt][r];
        if (cg < 512){
          out[((size_t)b_*1024 + t)*512 + cg] = v + bm[cg];
        } else {
          float x = v + bc[cg - 512];
          float sp = fmaxf(x, 0.f) + log1pf(__expf(-fabsf(x)));
          out[(size_t)16777216 + ((size_t)b_*1024 + t)*512 + (cg - 512)] = sp;
        }
      }
    }
  }
}

extern "C" void kernel_launch(void* const* d_in, const int* in_sizes, int n_in,
                              void* d_out, int out_size, void* d_ws, size_t ws_size,
                              hipStream_t stream)
{
  const float* obs = (const float*)d_in[0];
  const float* W1x = (const float*)d_in[1];
  const float* W1h = (const float*)d_in[2];
  const float* b1  = (const float*)d_in[3];
  const float* W2x = (const float*)d_in[4];
  const float* W2h = (const float*)d_in[5];
  const float* b2  = (const float*)d_in[6];
  const float* Wm  = (const float*)d_in[7];
  const float* bm  = (const float*)d_in[8];
  const float* Wc  = (const float*)d_in[9];
  const float* bc  = (const float*)d_in[10];
  float* out = (float*)d_out;

  char* wsb = (char*)d_ws;
  unsigned* flags      = (unsigned*)wsb;                      // 256 flags x 64B = 16KB
  unsigned short* h1   = (unsigned short*)(wsb + 16384);      // [1025][32][1024] bf16
  unsigned short* h2   = h1 + (size_t)1025*32768;             // [1025][32][1024] bf16
  unsigned short* obsb = h2 + (size_t)1025*32768;             // [1024][32][256]  bf16
  unsigned short* wht  = obsb + (size_t)1024*8192;            // [1024][1024]     bf16

  hipMemsetAsync(flags, 0, 16384, stream);
  hipMemsetAsync(h1, 0, 65536, stream);   // h1 slot 0 = h_{-1} = 0
  hipMemsetAsync(h2, 0, 65536, stream);   // h2 slot 0 = 0

  obs_conv <<<8192, 256, 0, stream>>>(obs, obsb);
  head_pack<<<4096, 256, 0, stream>>>(Wm, Wc, wht);

  const unsigned short* obsb_c = obsb;
  void* kargs[] = { (void*)&obsb_c, (void*)&h1, (void*)&h2,
                    (void*)&W1x, (void*)&W1h, (void*)&b1,
                    (void*)&W2x, (void*)&W2h, (void*)&b2, (void*)&flags };
  hipLaunchCooperativeKernel((void*)lstm_persist, dim3(NBLK), dim3(512), kargs, 0, stream);

  const unsigned short* Ah = h2 + 32768;   // h2 slots 1..1024 -> [32768,1024]
  heads_gemm<<<dim3(256, 8), 256, 0, stream>>>(Ah, wht, bm, bc, out);
}